// Round 18
// baseline (159.320 us; speedup 1.0000x reference)
//
#include <hip/hip_runtime.h>
#include <hip/hip_bf16.h>
#include <stdint.h>
#include <stddef.h>

typedef __attribute__((ext_vector_type(8))) short bf16x8;   // 8 bf16 (4 VGPR)
typedef __attribute__((ext_vector_type(4))) short short4v;  // 4 bf16
typedef __attribute__((ext_vector_type(4))) float f32x4;

#define DEV static __device__ __forceinline__

DEV float bf2f(short s) {
  union { unsigned int u; float f; } c;
  c.u = ((unsigned int)(unsigned short)s) << 16;
  return c.f;
}
DEV short f2bf(float f) {  // round-to-nearest-even
  union { float f; unsigned int u; } c; c.f = f;
  c.u += 0x7fffu + ((c.u >> 16) & 1);
  return (short)(c.u >> 16);
}
DEV unsigned int cvtpk_bf16(float lo, float hi) {  // word = {lo:bf16, hi:bf16<<16}, RNE
  unsigned int r;
  asm("v_cvt_pk_bf16_f32 %0, %1, %2" : "=v"(r) : "v"(lo), "v"(hi));
  return r;
}

// ---------------- fused prep: batched f32->bf16 convert + transposed convert ----------------
// Blocks < 2048: grid-stride vectorized cvt over a.j[0..n).
// Blocks >= 2048 (768 of them): 64x64 transpose-cvt tiles of W_Q/W_K/W_V
// (dst[k][d] = bf16(src[d][k])) via LDS [64][65] (conflict-free col reads).
struct CvtJob { const float* src; short* dst; int n4; };
struct PrepArgs {
  CvtJob j[8]; int n;
  const float* tsrc[3]; short* tdst[3];
};

__global__ __launch_bounds__(256) void prep_kernel(PrepArgs a) {
  __shared__ float tile[64][65];
  int bx = blockIdx.x;
  if (bx < 2048) {
    int tid = bx * 256 + threadIdx.x;
    int stride = 2048 * 256;
    for (int jj = 0; jj < a.n; ++jj) {
      const float4* s = (const float4*)a.j[jj].src;
      short4v* d = (short4v*)a.j[jj].dst;
      int n4 = a.j[jj].n4;
      for (int i = tid; i < n4; i += stride) {
        float4 v = s[i];
        short4v o = { f2bf(v.x), f2bf(v.y), f2bf(v.z), f2bf(v.w) };
        d[i] = o;
      }
    }
  } else {
    int id = bx - 2048;            // 0..767
    int z = id >> 8;               // 0..2
    int rem = id & 255;
    const float* src = a.tsrc[z];
    short* dst = a.tdst[z];
    int bi = (rem >> 4) * 64;      // row base (d)
    int bj = (rem & 15) * 64;      // col base (k)
    int t = threadIdx.x;
    int r0 = t >> 4;               // 0..15
    int c4 = (t & 15) * 4;         // 0..60
    #pragma unroll
    for (int rr = 0; rr < 4; ++rr) {
      int r = rr * 16 + r0;
      float4 v = *(const float4*)&src[(size_t)(bi + r) * 1024 + bj + c4];
      tile[r][c4] = v.x; tile[r][c4 + 1] = v.y; tile[r][c4 + 2] = v.z; tile[r][c4 + 3] = v.w;
    }
    __syncthreads();
    #pragma unroll
    for (int ww = 0; ww < 4; ++ww) {
      int orow = ww * 16 + r0;     // k within tile
      short4v o = { f2bf(tile[c4][orow]), f2bf(tile[c4 + 1][orow]),
                    f2bf(tile[c4 + 2][orow]), f2bf(tile[c4 + 3][orow]) };
      *(short4v*)&dst[(size_t)(bj + orow) * 1024 + bi + c4] = o;
    }
  }
}

// ---------------- bf16 GEMM, C = A * B^T (B stored [N][K]) ----------------
// BM x 128 tile (BM = 128 or 64), BK=64, 4 waves, 16x16x32 MFMA.
//   BM=128: wave grid 2x2, each 64x64 (acc[4][4]); 8 loads/step -> vmcnt(8);
//           LDS 64 KB dbuf -> 2 blocks/CU.
//   BM=64:  wave grid 1x4, each 64x32 (acc[4][2]); 6 loads/step -> vmcnt(6);
//           LDS 48 KB dbuf -> 3 blocks/CU. Used where extra occupancy, grid
//           doubling, or K-depth pays: weight-combine (384), projection
//           (768 = 3x256 = one full round), WO-proj (split-K x2, 8 K-steps),
//           MLP-down (split-K x2, 32 K-steps, half the partial traffic).
// DBUF=true: 2-phase double-buffered pipeline with COUNTED vmcnt (T4).
// Staging: global_load_lds dwordx4, linear LDS dest; source-side XOR swizzle
// (chunk ^= row&7) matched on the ds_read side (rule #21).
// SWZ: XCD-chunked block remap (T1) for N=1024-shaped launches.
// Per-z K-offset via kb[6] (split-K and/or operand batching share z).
// LESSONS: >= 2 blocks/CU or bust (round 3); no device-scope fences inside
// L2-reuse kernels (round 10); split-K partials are FULL M x N (round 13).
struct GemmArgs {
  const short* A[6];
  const short* B[6];
  void* C[6];
  const float* bias;
  int M, N, K, klen;
  int kb[6];
};

// EPI: 0 bf16 store, 1 +bias+relu bf16, 2 bf16 partial store (split-K, LN-consumed),
//      3 bf16 C^T store, 4 per-z (z<2: bf16 store, z==2: bf16 C^T store)
template<int EPI, bool SWZ, bool DBUF, int BM = 128>
__global__ __launch_bounds__(256) void gemm_bt(GemmArgs g) {
  __shared__ alignas(16) short As[DBUF ? 2 : 1][BM * 64];
  __shared__ alignas(16) short Bs[DBUF ? 2 : 1][128 * 64];
  constexpr int NI = (BM == 128) ? 4 : 2;   // 16-col fragments per wave
  constexpr int AL = BM / 32;               // A-loads per wave per K-step

  int bx, by, z;
  if (SWZ) {
    int gx = gridDim.x, gy = gridDim.y;
    int nwg = gx * gy * gridDim.z;
    int id = (blockIdx.z * gy + blockIdx.y) * gx + blockIdx.x;
    int tile = (id & 7) * (nwg >> 3) + (id >> 3);   // bijective (nwg%8==0)
    bx = tile % gx; int rem = tile / gx; by = rem % gy; z = rem / gy;
  } else {
    bx = blockIdx.x; by = blockIdx.y; z = blockIdx.z;
  }

  const short* A = g.A[z];
  const short* B = g.B[z];
  int kb = g.kb[z];

  int tid = threadIdx.x;
  int lane = tid & 63, wid = tid >> 6;
  int l15 = lane & 15, l4 = lane >> 4;
  int wr = (BM == 128) ? (wid >> 1) * 64 : 0;
  int wc = (BM == 128) ? (wid & 1) * 64 : wid * 32;
  int K = g.K, N = g.N;

  const short* Ab = A + (size_t)(by * BM) * K + kb;
  const short* Bb = B + (size_t)(bx * 128) * K + kb;

  int sR = lane >> 3;               // 0..7
  int sC = ((lane & 7) ^ sR) * 8;   // element offset in row (source-side swizzle)

  auto stage = [&](int buf, int k0) {
    const short* Abk = Ab + k0;
    const short* Bbk = Bb + k0;
    #pragma unroll
    for (int i = 0; i < AL; ++i) {
      int rbase = (wid * AL + i) * 8;
      __builtin_amdgcn_global_load_lds(
          (const __attribute__((address_space(1))) void*)(Abk + (size_t)(rbase + sR) * K + sC),
          (__attribute__((address_space(3))) void*)&As[buf][rbase * 64], 16, 0, 0);
    }
    #pragma unroll
    for (int i = 0; i < 4; ++i) {
      int rbase = (wid * 4 + i) * 8;
      __builtin_amdgcn_global_load_lds(
          (const __attribute__((address_space(1))) void*)(Bbk + (size_t)(rbase + sR) * K + sC),
          (__attribute__((address_space(3))) void*)&Bs[buf][rbase * 64], 16, 0, 0);
    }
  };

  f32x4 acc[4][NI] = {};
  int rj = l15 & 7;

  auto compute = [&](int buf) {
    bf16x8 af[2][4], bfr[2][NI];
    #pragma unroll
    for (int kk = 0; kk < 2; ++kk) {
      #pragma unroll
      for (int mi = 0; mi < 4; ++mi) {
        int r = wr + mi * 16 + l15;
        af[kk][mi] = *(const bf16x8*)&As[buf][r * 64 + (((kk << 2) | l4) ^ rj) * 8];
      }
      #pragma unroll
      for (int ni = 0; ni < NI; ++ni) {
        int r = wc + ni * 16 + l15;
        bfr[kk][ni] = *(const bf16x8*)&Bs[buf][r * 64 + (((kk << 2) | l4) ^ rj) * 8];
      }
    }
    #pragma unroll
    for (int kk = 0; kk < 2; ++kk)
      #pragma unroll
      for (int mi = 0; mi < 4; ++mi)
        #pragma unroll
        for (int ni = 0; ni < NI; ++ni)
          acc[mi][ni] = __builtin_amdgcn_mfma_f32_16x16x32_bf16(af[kk][mi], bfr[kk][ni], acc[mi][ni], 0, 0, 0);
  };

  if (DBUF) {
    stage(0, 0);   // AL+4 loads in flight
    int cur = 0;
    for (int k0 = 0; k0 < g.klen; k0 += 64) {
      if (k0 + 64 < g.klen) {
        stage(cur ^ 1, k0 + 64);   // +AL+4 loads; oldest AL+4 = cur tile
        if constexpr (BM == 128)
          asm volatile("s_waitcnt vmcnt(8)" ::: "memory");
        else
          asm volatile("s_waitcnt vmcnt(6)" ::: "memory");
      } else {
        asm volatile("s_waitcnt vmcnt(0)" ::: "memory");  // last tile: full drain
      }
      __builtin_amdgcn_s_barrier();   // all waves: cur tile staged

      compute(cur);

      asm volatile("" ::: "memory");  // pin ds_reads before the barrier
      __builtin_amdgcn_s_barrier();   // reads of cur done -> next stage may overwrite
      cur ^= 1;
    }
  } else {
    for (int k0 = 0; k0 < g.klen; k0 += 64) {
      __syncthreads();
      stage(0, k0);
      __syncthreads();
      compute(0);
    }
  }

  // epilogue: C/D layout col=lane&15, row=(lane>>4)*4+reg
  #pragma unroll
  for (int mi = 0; mi < 4; ++mi) {
    #pragma unroll
    for (int ni = 0; ni < NI; ++ni) {
      int col = bx * 128 + wc + ni * 16 + l15;
      float bv = 0.f;
      if (EPI == 1) bv = g.bias[col];
      bool ct = (EPI == 3) || (EPI == 4 && z == 2);
      if (ct) {
        // C^T store: 4 consecutive rows contiguous -> b64 store
        int row0 = by * BM + wr + mi * 16 + l4 * 4;
        short4v o4 = { f2bf(acc[mi][ni][0]), f2bf(acc[mi][ni][1]),
                       f2bf(acc[mi][ni][2]), f2bf(acc[mi][ni][3]) };
        *(short4v*)&((short*)g.C[z])[(size_t)col * g.M + row0] = o4;
      } else {
        #pragma unroll
        for (int j = 0; j < 4; ++j) {
          int row = by * BM + wr + mi * 16 + l4 * 4 + j;
          float v = acc[mi][ni][j];
          if (EPI == 0 || EPI == 4) {
            ((short*)g.C[z])[(size_t)row * N + col] = f2bf(v);
          } else if (EPI == 1) {
            v = fmaxf(v + bv, 0.f);
            ((short*)g.C[z])[(size_t)row * N + col] = f2bf(v);
          } else {
            // bf16 partial (consumed by LayerNorm -> relative error washes out)
            ((short*)g.C[z])[(size_t)row * N + col] = f2bf(v);
          }
        }
      }
    }
  }
}

// ---------------- causal flash attention, split over t (flash-decode) ----------------
// Round-8 proven structure; chunk size 12 K/V-tiles (round-17: neutral vs 8,
// kept as marginally better). Grid 16 heads x 60 chunks = 960 blocks,
// fully resident at 4 blocks/CU. chunks(qb) = qb/12 + 1.
// q,k: [S][H*64] bf16 ; vt: [H*64][S] bf16 (V transposed) ; o: [S][H*64].
// LDS = Ks 16K + Vs 16K + Ps 8K = 40960 B -> 4 blocks/CU (16 waves).
// Counted-vmcnt 2-barrier pipeline (4 loads/wave/tile -> vmcnt(4)).
// Ps XOR-swizzled (byte ^= (l15&7)<<4), same-wave write/read (rule #21).
// Softmax VALU cuts: v_cvt_pk_bf16_f32 (T12) + defer-max THR=8 (T13).
// SEPARATE attn_combine dispatch (no device-scope fences — round-10 lesson).
__global__ __launch_bounds__(256, 4) void flash_attn(
    const short* __restrict__ q, const short* __restrict__ k,
    const short* __restrict__ vt, short* __restrict__ o,
    short* __restrict__ Opart, float* __restrict__ Ml)
{
  const int HD = 1024, SS = 2048;
  int h = blockIdx.x;          // 0..15
  int cid = blockIdx.y;        // 0..59
  // decode chunk-id -> (qb, cx); chunks(qb) = qb/12 + 1
  int qb = 0, cx = cid;
  while (cx >= qb / 12 + 1) { cx -= qb / 12 + 1; ++qb; }
  int nch = qb / 12 + 1;
  int tf = cx * 12;                 // first K/V tile of this chunk
  int tl = min(qb, tf + 11);        // last tile (inclusive)
  int qbase = qb << 6;

  int tid = threadIdx.x;
  int wid = tid >> 6, lane = tid & 63;
  int l15 = lane & 15, l4 = lane >> 4;

  __shared__ alignas(16) short Ks[2][64 * 64];
  __shared__ alignas(16) short Vs[2][64 * 64];   // V^T tile: row e, col t
  __shared__ alignas(16) char PsB[4][2048];      // per-wave P [16 q][64 t] bf16, XOR-swizzled

  // Q fragment, pre-scaled by 0.125*log2(e) (exp2-domain softmax)
  bf16x8 qf[2];
  {
    int qr = qbase + wid * 16 + l15;
    const short* qp = q + (size_t)qr * HD + h * 64 + l4 * 8;
    bf16x8 r0 = *(const bf16x8*)qp;
    bf16x8 r1 = *(const bf16x8*)(qp + 32);
    const float SC = 0.1803368801f;  // 0.125 * log2(e)
    #pragma unroll
    for (int j = 0; j < 8; ++j) {
      qf[0][j] = f2bf(bf2f(r0[j]) * SC);
      qf[1][j] = f2bf(bf2f(r1[j]) * SC);
    }
  }

  int sR = lane >> 3;          // staging row within 8-row group
  int sC = (lane & 7) ^ sR;    // swizzled 16B chunk (source side)

  auto stage = [&](int buf, int t0) {
    const short* kbase = k + (size_t)t0 * HD + h * 64;
    const short* vbase = vt + (size_t)(h * 64) * SS + t0;
    #pragma unroll
    for (int i = 0; i < 2; ++i) {
      int rb = wid * 16 + i * 8;
      __builtin_amdgcn_global_load_lds(
          (const __attribute__((address_space(1))) void*)(kbase + (size_t)(rb + sR) * HD + sC * 8),
          (__attribute__((address_space(3))) void*)&Ks[buf][rb * 64], 16, 0, 0);
      __builtin_amdgcn_global_load_lds(
          (const __attribute__((address_space(1))) void*)(vbase + (size_t)(rb + sR) * SS + sC * 8),
          (__attribute__((address_space(3))) void*)&Vs[buf][rb * 64], 16, 0, 0);
    }
  };

  f32x4 oacc[4] = {};
  float mrun = -1e30f, lrun = 0.f;
  int q_g = qbase + wid * 16 + l15;
  int sbase = (lane & 48) + ((lane & 48) >> 2);  // lane l4*16 + l4*4 (+j) for redistribution

  char* Pw = &PsB[wid][l15 << 7];   // this lane's P row base (bytes)
  int swz = (l15 & 7) << 4;         // XOR swizzle within the 128B row

  stage(0, tf << 6);   // 4 loads in flight
  int cur = 0;

  for (int tt = tf; tt <= tl; ++tt) {
    if (tt < tl) {
      stage(cur ^ 1, (tt + 1) << 6);                   // +4 loads (8 in flight)
      asm volatile("s_waitcnt vmcnt(4)" ::: "memory"); // oldest 4 = cur tile
    } else {
      asm volatile("s_waitcnt vmcnt(0)" ::: "memory");
    }
    __builtin_amdgcn_s_barrier();   // cur tile staged for all waves

    const short* KsB = &Ks[cur][0];
    const short* VsB = &Vs[cur][0];
    int t0 = tt << 6;

    // S^T[t][q] = mfma(K rows, Q rows); lane: col=l15=q, row t=l4*4+j per ns
    f32x4 sc[4] = {};
    __builtin_amdgcn_s_setprio(1);
    #pragma unroll
    for (int ks = 0; ks < 2; ++ks)
      #pragma unroll
      for (int ns = 0; ns < 4; ++ns) {
        int r = ns * 16 + l15;
        bf16x8 kf = *(const bf16x8*)&KsB[r * 64 + (((ks << 2) | l4) ^ (r & 7)) * 8];
        sc[ns] = __builtin_amdgcn_mfma_f32_16x16x32_bf16(kf, qf[ks], sc[ns], 0, 0, 0);
      }
    __builtin_amdgcn_s_setprio(0);

    if (tt == qb) {  // diagonal tile: mask t > q
      #pragma unroll
      for (int ns = 0; ns < 4; ++ns)
        #pragma unroll
        for (int j = 0; j < 4; ++j) {
          int t_g = t0 + ns * 16 + l4 * 4 + j;
          if (t_g > q_g) sc[ns][j] = -1e30f;
        }
    }

    // online softmax over t for this lane's q (16 local + 2 shfl)
    float mloc = sc[0][0];
    #pragma unroll
    for (int ns = 0; ns < 4; ++ns)
      #pragma unroll
      for (int j = 0; j < 4; ++j) mloc = fmaxf(mloc, sc[ns][j]);
    mloc = fmaxf(mloc, __shfl_xor(mloc, 16, 64));
    mloc = fmaxf(mloc, __shfl_xor(mloc, 32, 64));

    // defer-max (T13): skip O-rescale when max growth <= 8 (exp2 domain);
    // P then bounded by 2^8, f32 accum fine; combine math is mrun-agnostic.
    if (!__all(mloc - mrun <= 8.0f)) {
      float mnew = fmaxf(mrun, mloc);
      float sco = exp2f(mrun - mnew);
      float scR[4];
      #pragma unroll
      for (int j = 0; j < 4; ++j) scR[j] = __shfl(sco, sbase + j, 64);
      #pragma unroll
      for (int es = 0; es < 4; ++es)
        #pragma unroll
        for (int j = 0; j < 4; ++j) oacc[es][j] *= scR[j];
      lrun *= sco;
      mrun = mnew;
    }

    float psum = 0.f;
    float p[4][4];
    #pragma unroll
    for (int ns = 0; ns < 4; ++ns)
      #pragma unroll
      for (int j = 0; j < 4; ++j) {
        p[ns][j] = exp2f(sc[ns][j] - mrun);
        psum += p[ns][j];
      }
    psum += __shfl_xor(psum, 16, 64);
    psum += __shfl_xor(psum, 32, 64);
    lrun += psum;

    // P -> LDS via cvt_pk, b64 swizzled store (lane owns t = ns*16 + l4*4 ..+4)
    #pragma unroll
    for (int ns = 0; ns < 4; ++ns) {
      uint2 pv = { cvtpk_bf16(p[ns][0], p[ns][1]), cvtpk_bf16(p[ns][2], p[ns][3]) };
      *(uint2*)&Pw[((ns << 5) | (l4 << 3)) ^ swz] = pv;
    }

    // PV: O[q][e] += P[q,t] . V[t,e]  (B-frag = V^T rows from Vs)
    __builtin_amdgcn_s_setprio(1);
    #pragma unroll
    for (int ks = 0; ks < 2; ++ks) {
      bf16x8 pf = *(const bf16x8*)&Pw[((ks << 6) | (l4 << 4)) ^ swz];
      #pragma unroll
      for (int es = 0; es < 4; ++es) {
        int r = es * 16 + l15;
        bf16x8 vf = *(const bf16x8*)&VsB[r * 64 + (((ks << 2) | l4) ^ (r & 7)) * 8];
        oacc[es] = __builtin_amdgcn_mfma_f32_16x16x32_bf16(pf, vf, oacc[es], 0, 0, 0);
      }
    }
    __builtin_amdgcn_s_setprio(0);

    asm volatile("" ::: "memory");  // pin LDS reads before the barrier
    __builtin_amdgcn_s_barrier();   // reads of cur done -> next stage may overwrite
    cur ^= 1;
  }

  if (nch == 1) {
    // single-chunk q-tile: normalize and write final O
    float linv = 1.f / lrun;
    float invR[4];
    #pragma unroll
    for (int j = 0; j < 4; ++j) invR[j] = __shfl(linv, sbase + j, 64);
    #pragma unroll
    for (int es = 0; es < 4; ++es)
      #pragma unroll
      for (int j = 0; j < 4; ++j) {
        int row = qbase + wid * 16 + l4 * 4 + j;
        o[(size_t)row * HD + h * 64 + es * 16 + l15] = f2bf(oacc[es][j] * invR[j]);
      }
  } else {
    // partial: unnormalized O (bf16: rel err ~0.4%, removed by combine/LN)
    // + per-row m,l (f32) for the combine pass
    size_t slot = (size_t)h * 60 + cid;
    short* op = Opart + slot * 4096;
    #pragma unroll
    for (int es = 0; es < 4; ++es)
      #pragma unroll
      for (int j = 0; j < 4; ++j) {
        int row = wid * 16 + l4 * 4 + j;
        op[row * 64 + es * 16 + l15] = f2bf(oacc[es][j]);
      }
    if (l4 == 0) {
      Ml[slot * 128 + wid * 16 + l15] = mrun;
      Ml[slot * 128 + 64 + wid * 16 + l15] = lrun;
    }
  }
}

// ---------------- combine partial attention chunks ----------------
// One block per (head, qb>=12). nch in {2,3}. Per q-row: M = max m_k,
// w_k = 2^(m_k - M), L = sum w_k l_k, O = (sum w_k Opart_k) / L.
__global__ __launch_bounds__(256) void attn_combine(
    const short* __restrict__ Opart, const float* __restrict__ Ml,
    short* __restrict__ o)
{
  const int HD = 1024;
  int h = blockIdx.x;         // 0..15
  int qb = 12 + blockIdx.y;   // 12..31
  int nch = qb / 12 + 1;
  int cb = 0;
  for (int qq = 0; qq < qb; ++qq) cb += qq / 12 + 1;  // first chunk-id of qb
  int tid = threadIdx.x;
  int r = tid >> 2;             // row 0..63
  int cq = (tid & 3) << 4;      // col base 0/16/32/48
  size_t slot0 = (size_t)h * 60 + cb;

  float mk[3], lk[3];
  float M = -1e30f;
  #pragma unroll
  for (int kk = 0; kk < 3; ++kk) {
    bool en = kk < nch;
    mk[kk] = en ? Ml[(slot0 + kk) * 128 + r] : -1e30f;
    lk[kk] = en ? Ml[(slot0 + kk) * 128 + 64 + r] : 0.f;
    M = fmaxf(M, mk[kk]);
  }
  float L = 0.f, w[3];
  #pragma unroll
  for (int kk = 0; kk < 3; ++kk) { w[kk] = exp2f(mk[kk] - M); L += w[kk] * lk[kk]; }

  float acc[16] = {};
  #pragma unroll
  for (int kk = 0; kk < 3; ++kk) {
    if (kk < nch) {
      const short* op = Opart + (slot0 + kk) * 4096 + r * 64 + cq;
      float wk = w[kk];
      #pragma unroll
      for (int c4 = 0; c4 < 4; ++c4) {
        short4v v = *(const short4v*)&op[c4 * 4];
        acc[c4 * 4 + 0] += wk * bf2f(v[0]);
        acc[c4 * 4 + 1] += wk * bf2f(v[1]);
        acc[c4 * 4 + 2] += wk * bf2f(v[2]);
        acc[c4 * 4 + 3] += wk * bf2f(v[3]);
      }
    }
  }
  float inv = 1.f / L;
  int orow = (qb << 6) + r;
  short* dst = o + (size_t)orow * HD + h * 64 + cq;
  #pragma unroll
  for (int c4 = 0; c4 < 4; ++c4) {
    short4v ov = { f2bf(acc[c4 * 4 + 0] * inv), f2bf(acc[c4 * 4 + 1] * inv),
                   f2bf(acc[c4 * 4 + 2] * inv), f2bf(acc[c4 * 4 + 3] * inv) };
    *(short4v*)&dst[c4 * 4] = ov;
  }
}

// ---------------- LayerNorm + residual ----------------
// Both LN kernels take 2 bf16 partials (WO-proj and MLP-down are split-K x2).
// E residual read as bf16 (Ebf); x1 kept bf16-only (x1b).
__global__ __launch_bounds__(256) void ln_res1(
    const short* __restrict__ P0, const short* __restrict__ P1,
    const short* __restrict__ Eb,
    const float* __restrict__ gamma, const float* __restrict__ beta,
    short* __restrict__ x1b)
{
  int row = blockIdx.x, tid = threadIdx.x;
  int lane = tid & 63, wid = tid >> 6;
  size_t idx = (size_t)row * 1024 + tid * 4;
  short4v p0 = *(const short4v*)&P0[idx];
  short4v p1 = *(const short4v*)&P1[idx];
  float a[4];
  #pragma unroll
  for (int j = 0; j < 4; ++j)
    a[j] = bf2f(p0[j]) + bf2f(p1[j]);
  float s = a[0] + a[1] + a[2] + a[3];
  float q = a[0]*a[0] + a[1]*a[1] + a[2]*a[2] + a[3]*a[3];
  #pragma unroll
  for (int off = 1; off < 64; off <<= 1) { s += __shfl_xor(s, off, 64); q += __shfl_xor(q, off, 64); }
  __shared__ float red[8];
  if (lane == 0) { red[wid] = s; red[4 + wid] = q; }
  __syncthreads();
  s = red[0] + red[1] + red[2] + red[3];
  q = red[4] + red[5] + red[6] + red[7];
  float mean = s * (1.f / 1024.f);
  float var = q * (1.f / 1024.f) - mean * mean;
  float rstd = rsqrtf(var + 1e-5f);
  short4v ev = *(const short4v*)&Eb[idx];
  float4 gv = *(const float4*)&gamma[tid * 4];
  float4 bv = *(const float4*)&beta[tid * 4];
  float o0 = bf2f(ev[0]) + gv.x * (a[0] - mean) * rstd + bv.x;
  float o1 = bf2f(ev[1]) + gv.y * (a[1] - mean) * rstd + bv.y;
  float o2 = bf2f(ev[2]) + gv.z * (a[2] - mean) * rstd + bv.z;
  float o3 = bf2f(ev[3]) + gv.w * (a[3] - mean) * rstd + bv.w;
  short4v xb = { f2bf(o0), f2bf(o1), f2bf(o2), f2bf(o3) };
  *(short4v*)&x1b[idx] = xb;
}

__global__ __launch_bounds__(256) void ln_res2(
    const short* __restrict__ M0, const short* __restrict__ M1,
    const float* __restrict__ bias, const short* __restrict__ x1b,
    const float* __restrict__ gamma, const float* __restrict__ beta,
    float* __restrict__ out)
{
  int row = blockIdx.x, tid = threadIdx.x;
  int lane = tid & 63, wid = tid >> 6;
  size_t idx = (size_t)row * 1024 + tid * 4;
  short4v m0 = *(const short4v*)&M0[idx];
  short4v m1 = *(const short4v*)&M1[idx];
  float4 bb = *(const float4*)&bias[tid * 4];
  float a[4];
  a[0] = bf2f(m0[0]) + bf2f(m1[0]) + bb.x;
  a[1] = bf2f(m0[1]) + bf2f(m1[1]) + bb.y;
  a[2] = bf2f(m0[2]) + bf2f(m1[2]) + bb.z;
  a[3] = bf2f(m0[3]) + bf2f(m1[3]) + bb.w;
  float s = a[0] + a[1] + a[2] + a[3];
  float q = a[0]*a[0] + a[1]*a[1] + a[2]*a[2] + a[3]*a[3];
  #pragma unroll
  for (int off = 1; off < 64; off <<= 1) { s += __shfl_xor(s, off, 64); q += __shfl_xor(q, off, 64); }
  __shared__ float red[8];
  if (lane == 0) { red[wid] = s; red[4 + wid] = q; }
  __syncthreads();
  s = red[0] + red[1] + red[2] + red[3];
  q = red[4] + red[5] + red[6] + red[7];
  float mean = s * (1.f / 1024.f);
  float var = q * (1.f / 1024.f) - mean * mean;
  float rstd = rsqrtf(var + 1e-5f);
  short4v xv = *(const short4v*)&x1b[idx];
  float4 gv = *(const float4*)&gamma[tid * 4];
  float4 bv = *(const float4*)&beta[tid * 4];
  float4 ov = { bf2f(xv[0]) + gv.x * (a[0] - mean) * rstd + bv.x,
                bf2f(xv[1]) + gv.y * (a[1] - mean) * rstd + bv.y,
                bf2f(xv[2]) + gv.z * (a[2] - mean) * rstd + bv.z,
                bf2f(xv[3]) + gv.w * (a[3] - mean) * rstd + bv.w };
  *(float4*)&out[idx] = ov;
}

// ---------------- launch ----------------
extern "C" void kernel_launch(void* const* d_in, const int* in_sizes, int n_in,
                              void* d_out, int out_size, void* d_ws, size_t ws_size,
                              hipStream_t stream)
{
  (void)in_sizes; (void)n_in; (void)out_size;
  const int S = 2048, D = 1024, DM = 4096, H = 16;
  const size_t MB = 1u << 20;
  const float* E   = (const float*)d_in[0];
  const float* W_Q = (const float*)d_in[2];
  const float* W_K = (const float*)d_in[3];
  const float* W_V = (const float*)d_in[4];
  const float* W_O = (const float*)d_in[5];
  const float* H_Q = (const float*)d_in[6];
  const float* H_K = (const float*)d_in[7];
  const float* H_V = (const float*)d_in[8];
  const float* L1w = (const float*)d_in[9];
  const float* L1b = (const float*)d_in[10];
  const float* L2w = (const float*)d_in[11];
  const float* L2b = (const float*)d_in[12];
  const float* g1  = (const float*)d_in[13];
  const float* b1  = (const float*)d_in[14];
  const float* g2  = (const float*)d_in[15];
  const float* b2  = (const float*)d_in[16];

  char* base = (char*)d_ws;
  if (ws_size < 90 * MB) return;  // loud failure if workspace too small

  short* Ebf  = (short*)(base + 0 * MB);
  short* TWq  = (short*)(base + 4 * MB);   // W_Q^T bf16 [k][d]
  short* TWk  = (short*)(base + 6 * MB);
  short* TWv  = (short*)(base + 8 * MB);
  short* Wob  = (short*)(base + 10 * MB);
  short* Hqb  = (short*)(base + 12 * MB);
  short* Hkb  = (short*)(base + 14 * MB);
  short* Hvb  = (short*)(base + 16 * MB);
  short* L1wb = (short*)(base + 18 * MB);
  short* L2wb = (short*)(base + 26 * MB);
  short* Cq   = (short*)(base + 34 * MB);  // combined weight H_q @ W_Q, [e][k]
  short* Ck   = (short*)(base + 36 * MB);
  short* Cv   = (short*)(base + 38 * MB);
  short* qh   = (short*)(base + 46 * MB);
  short* kh   = (short*)(base + 50 * MB);
  short* vtb  = (short*)(base + 54 * MB);  // V^T per head: [H*64][S]
  short* obuf = (short*)(base + 58 * MB);
  short* x1b  = (short*)(base + 62 * MB);
  short* hbuf = (short*)(base + 74 * MB);  // [74,90)
  // WO-proj bf16 partials (split-K x2): alias hbuf region (dead then).
  short* WOP0 = (short*)(base + 74 * MB);
  short* WOP1 = (short*)(base + 82 * MB);
  // MLP-down bf16 partials (split-K x2): alias Cq..qh region (dead then).
  short* MP0  = (short*)(base + 34 * MB);
  short* MP1  = (short*)(base + 42 * MB);
  // attention partials: live ONLY between flash_attn and attn_combine.
  short* Opart = (short*)(base + 66 * MB);  // 960 slots x 64x64 bf16 = 7.5 MB
  float* Ml    = (float*)(base + 86 * MB);  // 960 x 128 f32 = 0.48 MB

  PrepArgs pa;
  pa.j[0] = { E,   Ebf,  S * D / 4 };
  pa.j[1] = { W_O, Wob,  D * D / 4 };
  pa.j[2] = { H_Q, Hqb,  D * D / 4 };
  pa.j[3] = { H_K, Hkb,  D * D / 4 };
  pa.j[4] = { H_V, Hvb,  D * D / 4 };
  pa.j[5] = { L1w, L1wb, DM * D / 4 };
  pa.j[6] = { L2w, L2wb, DM * D / 4 };
  pa.n = 7;
  pa.tsrc[0] = W_Q; pa.tsrc[1] = W_K; pa.tsrc[2] = W_V;
  pa.tdst[0] = TWq; pa.tdst[1] = TWk; pa.tdst[2] = TWv;
  prep_kernel<<<2048 + 768, 256, 0, stream>>>(pa);

  GemmArgs ga;

  // weight combine: C_x = H_x @ W_X (so x_head = E @ C_x^T), BM=64 tiles:
  // grid 8 x 16 x 3 = 384 blocks (1.5/CU) with NO split-K / NO fold.
  ga = {};
  ga.A[0] = Hqb; ga.A[1] = Hkb; ga.A[2] = Hvb;
  ga.B[0] = TWq; ga.B[1] = TWk; ga.B[2] = TWv;
  ga.C[0] = Cq;  ga.C[1] = Ck;  ga.C[2] = Cv;
  ga.M = D; ga.N = D; ga.K = D; ga.klen = D;
  for (int z = 0; z < 6; ++z) ga.kb[z] = 0;
  gemm_bt<0, true, true, 64><<<dim3(D / 128, D / 64, 3), 256, 0, stream>>>(ga);

  // fused projections: qh/kh (normal store) + vtb (transposed store), one
  // launch, BM=64: grid 8 x 32 x 3 = 768 blocks = 3 x 256 -> LDS 48 KB gives
  // 3 blocks/CU = EXACTLY one full round, counted-vmcnt pipeline retained.
  ga = {};
  ga.A[0] = Ebf; ga.A[1] = Ebf; ga.A[2] = Ebf;
  ga.B[0] = Cq;  ga.B[1] = Ck;  ga.B[2] = Cv;
  ga.C[0] = qh;  ga.C[1] = kh;  ga.C[2] = vtb;
  ga.M = S; ga.N = D; ga.K = D; ga.klen = D;
  for (int z = 0; z < 6; ++z) ga.kb[z] = 0;
  gemm_bt<4, true, true, 64><<<dim3(D / 128, S / 64, 3), 256, 0, stream>>>(ga);

  // causal attention, chunks of <=12 K/V-tiles (60 chunks/head, 960 blocks)
  flash_attn<<<dim3(H, 60), 256, 0, stream>>>(qh, kh, vtb, obuf, Opart, Ml);
  // combine chunks for q-tiles 12..31
  attn_combine<<<dim3(H, 20), 256, 0, stream>>>(Opart, Ml, obuf);

  // output projection, BM=64 + split-K x2 -> bf16 partials
  // (grid 8 x 32 x 2 = 512 blocks, klen 512 = 8 K-steps)
  ga = {};
  ga.A[0] = obuf; ga.A[1] = obuf;
  ga.B[0] = Wob;  ga.B[1] = Wob;
  ga.C[0] = WOP0; ga.C[1] = WOP1;
  ga.M = S; ga.N = D; ga.K = D; ga.klen = D / 2;
  for (int z = 0; z < 6; ++z) ga.kb[z] = (z & 1) * (D / 2);
  gemm_bt<2, true, true, 64><<<dim3(D / 128, S / 64, 2), 256, 0, stream>>>(ga);

  // LN1 + residual (bf16 E, 2 partials) -> bf16 x1
  ln_res1<<<S, 256, 0, stream>>>(WOP0, WOP1, Ebf, g1, b1, x1b);

  // MLP up + bias + relu (512 blocks, 2/CU) -> dbuf BM=128; swizzle OFF (N=4096)
  ga = {};
  ga.A[0] = x1b; ga.B[0] = L1wb; ga.C[0] = hbuf;
  ga.bias = L1b;
  ga.M = S; ga.N = DM; ga.K = D; ga.klen = D;
  for (int z = 0; z < 6; ++z) ga.kb[z] = 0;
  gemm_bt<1, false, true><<<dim3(DM / 128, S / 128, 1), 256, 0, stream>>>(ga);

  // MLP down, BM=64 + split-K x2 -> bf16 partials
  // (grid 8 x 32 x 2 = 512 blocks, klen 2048 = 32 K-steps; half the
  // partial traffic of the old BM=128 split-K x4)
  ga = {};
  ga.A[0] = hbuf; ga.A[1] = hbuf;
  ga.B[0] = L2wb; ga.B[1] = L2wb;
  ga.C[0] = MP0;  ga.C[1] = MP1;
  ga.M = S; ga.N = D; ga.K = DM; ga.klen = DM / 2;
  for (int z = 0; z < 6; ++z) ga.kb[z] = (z & 1) * (DM / 2);
  gemm_bt<2, true, true, 64><<<dim3(D / 128, S / 64, 2), 256, 0, stream>>>(ga);

  // LN2 + bias + residual (bf16 x1) -> out (f32)
  ln_res2<<<S, 256, 0, stream>>>(MP0, MP1, L2b, x1b, g2, b2, (float*)d_out);
}

// Round 19
// 153.761 us; speedup vs baseline: 1.0362x; 1.0362x over previous
//
#include <hip/hip_runtime.h>
#include <hip/hip_bf16.h>
#include <stdint.h>
#include <stddef.h>

typedef __attribute__((ext_vector_type(8))) short bf16x8;   // 8 bf16 (4 VGPR)
typedef __attribute__((ext_vector_type(4))) short short4v;  // 4 bf16
typedef __attribute__((ext_vector_type(4))) float f32x4;

#define DEV static __device__ __forceinline__

DEV float bf2f(short s) {
  union { unsigned int u; float f; } c;
  c.u = ((unsigned int)(unsigned short)s) << 16;
  return c.f;
}
DEV short f2bf(float f) {  // round-to-nearest-even
  union { float f; unsigned int u; } c; c.f = f;
  c.u += 0x7fffu + ((c.u >> 16) & 1);
  return (short)(c.u >> 16);
}
DEV unsigned int cvtpk_bf16(float lo, float hi) {  // word = {lo:bf16, hi:bf16<<16}, RNE
  unsigned int r;
  asm("v_cvt_pk_bf16_f32 %0, %1, %2" : "=v"(r) : "v"(lo), "v"(hi));
  return r;
}

// ---------------- fused prep: batched f32->bf16 convert + transposed convert ----------------
// Blocks < 2048: grid-stride vectorized cvt over a.j[0..n).
// Blocks >= 2048 (768 of them): 64x64 transpose-cvt tiles of W_Q/W_K/W_V
// (dst[k][d] = bf16(src[d][k])) via LDS [64][65] (conflict-free col reads).
struct CvtJob { const float* src; short* dst; int n4; };
struct PrepArgs {
  CvtJob j[8]; int n;
  const float* tsrc[3]; short* tdst[3];
};

__global__ __launch_bounds__(256) void prep_kernel(PrepArgs a) {
  __shared__ float tile[64][65];
  int bx = blockIdx.x;
  if (bx < 2048) {
    int tid = bx * 256 + threadIdx.x;
    int stride = 2048 * 256;
    for (int jj = 0; jj < a.n; ++jj) {
      const float4* s = (const float4*)a.j[jj].src;
      short4v* d = (short4v*)a.j[jj].dst;
      int n4 = a.j[jj].n4;
      for (int i = tid; i < n4; i += stride) {
        float4 v = s[i];
        short4v o = { f2bf(v.x), f2bf(v.y), f2bf(v.z), f2bf(v.w) };
        d[i] = o;
      }
    }
  } else {
    int id = bx - 2048;            // 0..767
    int z = id >> 8;               // 0..2
    int rem = id & 255;
    const float* src = a.tsrc[z];
    short* dst = a.tdst[z];
    int bi = (rem >> 4) * 64;      // row base (d)
    int bj = (rem & 15) * 64;      // col base (k)
    int t = threadIdx.x;
    int r0 = t >> 4;               // 0..15
    int c4 = (t & 15) * 4;         // 0..60
    #pragma unroll
    for (int rr = 0; rr < 4; ++rr) {
      int r = rr * 16 + r0;
      float4 v = *(const float4*)&src[(size_t)(bi + r) * 1024 + bj + c4];
      tile[r][c4] = v.x; tile[r][c4 + 1] = v.y; tile[r][c4 + 2] = v.z; tile[r][c4 + 3] = v.w;
    }
    __syncthreads();
    #pragma unroll
    for (int ww = 0; ww < 4; ++ww) {
      int orow = ww * 16 + r0;     // k within tile
      short4v o = { f2bf(tile[c4][orow]), f2bf(tile[c4 + 1][orow]),
                    f2bf(tile[c4 + 2][orow]), f2bf(tile[c4 + 3][orow]) };
      *(short4v*)&dst[(size_t)(bj + orow) * 1024 + bi + c4] = o;
    }
  }
}

// ---------------- bf16 GEMM, C = A * B^T (B stored [N][K]) ----------------
// BM x 128 tile (BM = 128 or 64), BK=64, 4 waves, 16x16x32 MFMA.
//   BM=128: wave grid 2x2, each 64x64 (acc[4][4]); 8 loads/step -> vmcnt(8);
//           LDS 64 KB dbuf -> 2 blocks/CU.
//   BM=64:  wave grid 1x4, each 64x32 (acc[4][2]); 6 loads/step -> vmcnt(6);
//           LDS 48 KB dbuf -> 3 blocks/CU.
// BM=64 SELECTION RULE (round-18 lesson): it pays ONLY when it buys
// occupancy/rounds (projection 768=3x256), grid doubling without split-K
// (weight-combine), or shallow-K partial reduction (WO-proj K=1024). For
// DEEP-K GEMMs (MLP-down K=4096) it raises staged bytes/FLOP by 1.5x
// (768KB vs 512KB per 33.5 MFLOP) and LOSES ~5 us. Keep BM=128 there.
// DBUF=true: 2-phase double-buffered pipeline with COUNTED vmcnt (T4).
// Staging: global_load_lds dwordx4, linear LDS dest; source-side XOR swizzle
// (chunk ^= row&7) matched on the ds_read side (rule #21).
// SWZ: XCD-chunked block remap (T1) for N=1024-shaped launches.
// Per-z K-offset via kb[6] (split-K and/or operand batching share z).
// LESSONS: >= 2 blocks/CU or bust (round 3); no device-scope fences inside
// L2-reuse kernels (round 10); split-K partials are FULL M x N (round 13).
struct GemmArgs {
  const short* A[6];
  const short* B[6];
  void* C[6];
  const float* bias;
  int M, N, K, klen;
  int kb[6];
};

// EPI: 0 bf16 store, 1 +bias+relu bf16, 2 bf16 partial store (split-K, LN-consumed),
//      3 bf16 C^T store, 4 per-z (z<2: bf16 store, z==2: bf16 C^T store)
template<int EPI, bool SWZ, bool DBUF, int BM = 128>
__global__ __launch_bounds__(256) void gemm_bt(GemmArgs g) {
  __shared__ alignas(16) short As[DBUF ? 2 : 1][BM * 64];
  __shared__ alignas(16) short Bs[DBUF ? 2 : 1][128 * 64];
  constexpr int NI = (BM == 128) ? 4 : 2;   // 16-col fragments per wave
  constexpr int AL = BM / 32;               // A-loads per wave per K-step

  int bx, by, z;
  if (SWZ) {
    int gx = gridDim.x, gy = gridDim.y;
    int nwg = gx * gy * gridDim.z;
    int id = (blockIdx.z * gy + blockIdx.y) * gx + blockIdx.x;
    int tile = (id & 7) * (nwg >> 3) + (id >> 3);   // bijective (nwg%8==0)
    bx = tile % gx; int rem = tile / gx; by = rem % gy; z = rem / gy;
  } else {
    bx = blockIdx.x; by = blockIdx.y; z = blockIdx.z;
  }

  const short* A = g.A[z];
  const short* B = g.B[z];
  int kb = g.kb[z];

  int tid = threadIdx.x;
  int lane = tid & 63, wid = tid >> 6;
  int l15 = lane & 15, l4 = lane >> 4;
  int wr = (BM == 128) ? (wid >> 1) * 64 : 0;
  int wc = (BM == 128) ? (wid & 1) * 64 : wid * 32;
  int K = g.K, N = g.N;

  const short* Ab = A + (size_t)(by * BM) * K + kb;
  const short* Bb = B + (size_t)(bx * 128) * K + kb;

  int sR = lane >> 3;               // 0..7
  int sC = ((lane & 7) ^ sR) * 8;   // element offset in row (source-side swizzle)

  auto stage = [&](int buf, int k0) {
    const short* Abk = Ab + k0;
    const short* Bbk = Bb + k0;
    #pragma unroll
    for (int i = 0; i < AL; ++i) {
      int rbase = (wid * AL + i) * 8;
      __builtin_amdgcn_global_load_lds(
          (const __attribute__((address_space(1))) void*)(Abk + (size_t)(rbase + sR) * K + sC),
          (__attribute__((address_space(3))) void*)&As[buf][rbase * 64], 16, 0, 0);
    }
    #pragma unroll
    for (int i = 0; i < 4; ++i) {
      int rbase = (wid * 4 + i) * 8;
      __builtin_amdgcn_global_load_lds(
          (const __attribute__((address_space(1))) void*)(Bbk + (size_t)(rbase + sR) * K + sC),
          (__attribute__((address_space(3))) void*)&Bs[buf][rbase * 64], 16, 0, 0);
    }
  };

  f32x4 acc[4][NI] = {};
  int rj = l15 & 7;

  auto compute = [&](int buf) {
    bf16x8 af[2][4], bfr[2][NI];
    #pragma unroll
    for (int kk = 0; kk < 2; ++kk) {
      #pragma unroll
      for (int mi = 0; mi < 4; ++mi) {
        int r = wr + mi * 16 + l15;
        af[kk][mi] = *(const bf16x8*)&As[buf][r * 64 + (((kk << 2) | l4) ^ rj) * 8];
      }
      #pragma unroll
      for (int ni = 0; ni < NI; ++ni) {
        int r = wc + ni * 16 + l15;
        bfr[kk][ni] = *(const bf16x8*)&Bs[buf][r * 64 + (((kk << 2) | l4) ^ rj) * 8];
      }
    }
    #pragma unroll
    for (int kk = 0; kk < 2; ++kk)
      #pragma unroll
      for (int mi = 0; mi < 4; ++mi)
        #pragma unroll
        for (int ni = 0; ni < NI; ++ni)
          acc[mi][ni] = __builtin_amdgcn_mfma_f32_16x16x32_bf16(af[kk][mi], bfr[kk][ni], acc[mi][ni], 0, 0, 0);
  };

  if (DBUF) {
    stage(0, 0);   // AL+4 loads in flight
    int cur = 0;
    for (int k0 = 0; k0 < g.klen; k0 += 64) {
      if (k0 + 64 < g.klen) {
        stage(cur ^ 1, k0 + 64);   // +AL+4 loads; oldest AL+4 = cur tile
        if constexpr (BM == 128)
          asm volatile("s_waitcnt vmcnt(8)" ::: "memory");
        else
          asm volatile("s_waitcnt vmcnt(6)" ::: "memory");
      } else {
        asm volatile("s_waitcnt vmcnt(0)" ::: "memory");  // last tile: full drain
      }
      __builtin_amdgcn_s_barrier();   // all waves: cur tile staged

      compute(cur);

      asm volatile("" ::: "memory");  // pin ds_reads before the barrier
      __builtin_amdgcn_s_barrier();   // reads of cur done -> next stage may overwrite
      cur ^= 1;
    }
  } else {
    for (int k0 = 0; k0 < g.klen; k0 += 64) {
      __syncthreads();
      stage(0, k0);
      __syncthreads();
      compute(0);
    }
  }

  // epilogue: C/D layout col=lane&15, row=(lane>>4)*4+reg
  #pragma unroll
  for (int mi = 0; mi < 4; ++mi) {
    #pragma unroll
    for (int ni = 0; ni < NI; ++ni) {
      int col = bx * 128 + wc + ni * 16 + l15;
      float bv = 0.f;
      if (EPI == 1) bv = g.bias[col];
      bool ct = (EPI == 3) || (EPI == 4 && z == 2);
      if (ct) {
        // C^T store: 4 consecutive rows contiguous -> b64 store
        int row0 = by * BM + wr + mi * 16 + l4 * 4;
        short4v o4 = { f2bf(acc[mi][ni][0]), f2bf(acc[mi][ni][1]),
                       f2bf(acc[mi][ni][2]), f2bf(acc[mi][ni][3]) };
        *(short4v*)&((short*)g.C[z])[(size_t)col * g.M + row0] = o4;
      } else {
        #pragma unroll
        for (int j = 0; j < 4; ++j) {
          int row = by * BM + wr + mi * 16 + l4 * 4 + j;
          float v = acc[mi][ni][j];
          if (EPI == 0 || EPI == 4) {
            ((short*)g.C[z])[(size_t)row * N + col] = f2bf(v);
          } else if (EPI == 1) {
            v = fmaxf(v + bv, 0.f);
            ((short*)g.C[z])[(size_t)row * N + col] = f2bf(v);
          } else {
            // bf16 partial (consumed by LayerNorm -> relative error washes out)
            ((short*)g.C[z])[(size_t)row * N + col] = f2bf(v);
          }
        }
      }
    }
  }
}

// ---------------- causal flash attention, split over t (flash-decode) ----------------
// Round-8 proven structure; chunk size 12 K/V-tiles (round-17: neutral vs 8,
// kept as marginally better). Grid 16 heads x 60 chunks = 960 blocks,
// fully resident at 4 blocks/CU. chunks(qb) = qb/12 + 1.
// q,k: [S][H*64] bf16 ; vt: [H*64][S] bf16 (V transposed) ; o: [S][H*64].
// LDS = Ks 16K + Vs 16K + Ps 8K = 40960 B -> 4 blocks/CU (16 waves).
// Counted-vmcnt 2-barrier pipeline (4 loads/wave/tile -> vmcnt(4)).
// Ps XOR-swizzled (byte ^= (l15&7)<<4), same-wave write/read (rule #21).
// Softmax VALU cuts: v_cvt_pk_bf16_f32 (T12) + defer-max THR=8 (T13).
// SEPARATE attn_combine dispatch (no device-scope fences — round-10 lesson).
__global__ __launch_bounds__(256, 4) void flash_attn(
    const short* __restrict__ q, const short* __restrict__ k,
    const short* __restrict__ vt, short* __restrict__ o,
    short* __restrict__ Opart, float* __restrict__ Ml)
{
  const int HD = 1024, SS = 2048;
  int h = blockIdx.x;          // 0..15
  int cid = blockIdx.y;        // 0..59
  // decode chunk-id -> (qb, cx); chunks(qb) = qb/12 + 1
  int qb = 0, cx = cid;
  while (cx >= qb / 12 + 1) { cx -= qb / 12 + 1; ++qb; }
  int nch = qb / 12 + 1;
  int tf = cx * 12;                 // first K/V tile of this chunk
  int tl = min(qb, tf + 11);        // last tile (inclusive)
  int qbase = qb << 6;

  int tid = threadIdx.x;
  int wid = tid >> 6, lane = tid & 63;
  int l15 = lane & 15, l4 = lane >> 4;

  __shared__ alignas(16) short Ks[2][64 * 64];
  __shared__ alignas(16) short Vs[2][64 * 64];   // V^T tile: row e, col t
  __shared__ alignas(16) char PsB[4][2048];      // per-wave P [16 q][64 t] bf16, XOR-swizzled

  // Q fragment, pre-scaled by 0.125*log2(e) (exp2-domain softmax)
  bf16x8 qf[2];
  {
    int qr = qbase + wid * 16 + l15;
    const short* qp = q + (size_t)qr * HD + h * 64 + l4 * 8;
    bf16x8 r0 = *(const bf16x8*)qp;
    bf16x8 r1 = *(const bf16x8*)(qp + 32);
    const float SC = 0.1803368801f;  // 0.125 * log2(e)
    #pragma unroll
    for (int j = 0; j < 8; ++j) {
      qf[0][j] = f2bf(bf2f(r0[j]) * SC);
      qf[1][j] = f2bf(bf2f(r1[j]) * SC);
    }
  }

  int sR = lane >> 3;          // staging row within 8-row group
  int sC = (lane & 7) ^ sR;    // swizzled 16B chunk (source side)

  auto stage = [&](int buf, int t0) {
    const short* kbase = k + (size_t)t0 * HD + h * 64;
    const short* vbase = vt + (size_t)(h * 64) * SS + t0;
    #pragma unroll
    for (int i = 0; i < 2; ++i) {
      int rb = wid * 16 + i * 8;
      __builtin_amdgcn_global_load_lds(
          (const __attribute__((address_space(1))) void*)(kbase + (size_t)(rb + sR) * HD + sC * 8),
          (__attribute__((address_space(3))) void*)&Ks[buf][rb * 64], 16, 0, 0);
      __builtin_amdgcn_global_load_lds(
          (const __attribute__((address_space(1))) void*)(vbase + (size_t)(rb + sR) * SS + sC * 8),
          (__attribute__((address_space(3))) void*)&Vs[buf][rb * 64], 16, 0, 0);
    }
  };

  f32x4 oacc[4] = {};
  float mrun = -1e30f, lrun = 0.f;
  int q_g = qbase + wid * 16 + l15;
  int sbase = (lane & 48) + ((lane & 48) >> 2);  // lane l4*16 + l4*4 (+j) for redistribution

  char* Pw = &PsB[wid][l15 << 7];   // this lane's P row base (bytes)
  int swz = (l15 & 7) << 4;         // XOR swizzle within the 128B row

  stage(0, tf << 6);   // 4 loads in flight
  int cur = 0;

  for (int tt = tf; tt <= tl; ++tt) {
    if (tt < tl) {
      stage(cur ^ 1, (tt + 1) << 6);                   // +4 loads (8 in flight)
      asm volatile("s_waitcnt vmcnt(4)" ::: "memory"); // oldest 4 = cur tile
    } else {
      asm volatile("s_waitcnt vmcnt(0)" ::: "memory");
    }
    __builtin_amdgcn_s_barrier();   // cur tile staged for all waves

    const short* KsB = &Ks[cur][0];
    const short* VsB = &Vs[cur][0];
    int t0 = tt << 6;

    // S^T[t][q] = mfma(K rows, Q rows); lane: col=l15=q, row t=l4*4+j per ns
    f32x4 sc[4] = {};
    __builtin_amdgcn_s_setprio(1);
    #pragma unroll
    for (int ks = 0; ks < 2; ++ks)
      #pragma unroll
      for (int ns = 0; ns < 4; ++ns) {
        int r = ns * 16 + l15;
        bf16x8 kf = *(const bf16x8*)&KsB[r * 64 + (((ks << 2) | l4) ^ (r & 7)) * 8];
        sc[ns] = __builtin_amdgcn_mfma_f32_16x16x32_bf16(kf, qf[ks], sc[ns], 0, 0, 0);
      }
    __builtin_amdgcn_s_setprio(0);

    if (tt == qb) {  // diagonal tile: mask t > q
      #pragma unroll
      for (int ns = 0; ns < 4; ++ns)
        #pragma unroll
        for (int j = 0; j < 4; ++j) {
          int t_g = t0 + ns * 16 + l4 * 4 + j;
          if (t_g > q_g) sc[ns][j] = -1e30f;
        }
    }

    // online softmax over t for this lane's q (16 local + 2 shfl)
    float mloc = sc[0][0];
    #pragma unroll
    for (int ns = 0; ns < 4; ++ns)
      #pragma unroll
      for (int j = 0; j < 4; ++j) mloc = fmaxf(mloc, sc[ns][j]);
    mloc = fmaxf(mloc, __shfl_xor(mloc, 16, 64));
    mloc = fmaxf(mloc, __shfl_xor(mloc, 32, 64));

    // defer-max (T13): skip O-rescale when max growth <= 8 (exp2 domain);
    // P then bounded by 2^8, f32 accum fine; combine math is mrun-agnostic.
    if (!__all(mloc - mrun <= 8.0f)) {
      float mnew = fmaxf(mrun, mloc);
      float sco = exp2f(mrun - mnew);
      float scR[4];
      #pragma unroll
      for (int j = 0; j < 4; ++j) scR[j] = __shfl(sco, sbase + j, 64);
      #pragma unroll
      for (int es = 0; es < 4; ++es)
        #pragma unroll
        for (int j = 0; j < 4; ++j) oacc[es][j] *= scR[j];
      lrun *= sco;
      mrun = mnew;
    }

    float psum = 0.f;
    float p[4][4];
    #pragma unroll
    for (int ns = 0; ns < 4; ++ns)
      #pragma unroll
      for (int j = 0; j < 4; ++j) {
        p[ns][j] = exp2f(sc[ns][j] - mrun);
        psum += p[ns][j];
      }
    psum += __shfl_xor(psum, 16, 64);
    psum += __shfl_xor(psum, 32, 64);
    lrun += psum;

    // P -> LDS via cvt_pk, b64 swizzled store (lane owns t = ns*16 + l4*4 ..+4)
    #pragma unroll
    for (int ns = 0; ns < 4; ++ns) {
      uint2 pv = { cvtpk_bf16(p[ns][0], p[ns][1]), cvtpk_bf16(p[ns][2], p[ns][3]) };
      *(uint2*)&Pw[((ns << 5) | (l4 << 3)) ^ swz] = pv;
    }

    // PV: O[q][e] += P[q,t] . V[t,e]  (B-frag = V^T rows from Vs)
    __builtin_amdgcn_s_setprio(1);
    #pragma unroll
    for (int ks = 0; ks < 2; ++ks) {
      bf16x8 pf = *(const bf16x8*)&Pw[((ks << 6) | (l4 << 4)) ^ swz];
      #pragma unroll
      for (int es = 0; es < 4; ++es) {
        int r = es * 16 + l15;
        bf16x8 vf = *(const bf16x8*)&VsB[r * 64 + (((ks << 2) | l4) ^ (r & 7)) * 8];
        oacc[es] = __builtin_amdgcn_mfma_f32_16x16x32_bf16(pf, vf, oacc[es], 0, 0, 0);
      }
    }
    __builtin_amdgcn_s_setprio(0);

    asm volatile("" ::: "memory");  // pin LDS reads before the barrier
    __builtin_amdgcn_s_barrier();   // reads of cur done -> next stage may overwrite
    cur ^= 1;
  }

  if (nch == 1) {
    // single-chunk q-tile: normalize and write final O
    float linv = 1.f / lrun;
    float invR[4];
    #pragma unroll
    for (int j = 0; j < 4; ++j) invR[j] = __shfl(linv, sbase + j, 64);
    #pragma unroll
    for (int es = 0; es < 4; ++es)
      #pragma unroll
      for (int j = 0; j < 4; ++j) {
        int row = qbase + wid * 16 + l4 * 4 + j;
        o[(size_t)row * HD + h * 64 + es * 16 + l15] = f2bf(oacc[es][j] * invR[j]);
      }
  } else {
    // partial: unnormalized O (bf16: rel err ~0.4%, removed by combine/LN)
    // + per-row m,l (f32) for the combine pass
    size_t slot = (size_t)h * 60 + cid;
    short* op = Opart + slot * 4096;
    #pragma unroll
    for (int es = 0; es < 4; ++es)
      #pragma unroll
      for (int j = 0; j < 4; ++j) {
        int row = wid * 16 + l4 * 4 + j;
        op[row * 64 + es * 16 + l15] = f2bf(oacc[es][j]);
      }
    if (l4 == 0) {
      Ml[slot * 128 + wid * 16 + l15] = mrun;
      Ml[slot * 128 + 64 + wid * 16 + l15] = lrun;
    }
  }
}

// ---------------- combine partial attention chunks ----------------
// One block per (head, qb>=12). nch in {2,3}. Per q-row: M = max m_k,
// w_k = 2^(m_k - M), L = sum w_k l_k, O = (sum w_k Opart_k) / L.
__global__ __launch_bounds__(256) void attn_combine(
    const short* __restrict__ Opart, const float* __restrict__ Ml,
    short* __restrict__ o)
{
  const int HD = 1024;
  int h = blockIdx.x;         // 0..15
  int qb = 12 + blockIdx.y;   // 12..31
  int nch = qb / 12 + 1;
  int cb = 0;
  for (int qq = 0; qq < qb; ++qq) cb += qq / 12 + 1;  // first chunk-id of qb
  int tid = threadIdx.x;
  int r = tid >> 2;             // row 0..63
  int cq = (tid & 3) << 4;      // col base 0/16/32/48
  size_t slot0 = (size_t)h * 60 + cb;

  float mk[3], lk[3];
  float M = -1e30f;
  #pragma unroll
  for (int kk = 0; kk < 3; ++kk) {
    bool en = kk < nch;
    mk[kk] = en ? Ml[(slot0 + kk) * 128 + r] : -1e30f;
    lk[kk] = en ? Ml[(slot0 + kk) * 128 + 64 + r] : 0.f;
    M = fmaxf(M, mk[kk]);
  }
  float L = 0.f, w[3];
  #pragma unroll
  for (int kk = 0; kk < 3; ++kk) { w[kk] = exp2f(mk[kk] - M); L += w[kk] * lk[kk]; }

  float acc[16] = {};
  #pragma unroll
  for (int kk = 0; kk < 3; ++kk) {
    if (kk < nch) {
      const short* op = Opart + (slot0 + kk) * 4096 + r * 64 + cq;
      float wk = w[kk];
      #pragma unroll
      for (int c4 = 0; c4 < 4; ++c4) {
        short4v v = *(const short4v*)&op[c4 * 4];
        acc[c4 * 4 + 0] += wk * bf2f(v[0]);
        acc[c4 * 4 + 1] += wk * bf2f(v[1]);
        acc[c4 * 4 + 2] += wk * bf2f(v[2]);
        acc[c4 * 4 + 3] += wk * bf2f(v[3]);
      }
    }
  }
  float inv = 1.f / L;
  int orow = (qb << 6) + r;
  short* dst = o + (size_t)orow * HD + h * 64 + cq;
  #pragma unroll
  for (int c4 = 0; c4 < 4; ++c4) {
    short4v ov = { f2bf(acc[c4 * 4 + 0] * inv), f2bf(acc[c4 * 4 + 1] * inv),
                   f2bf(acc[c4 * 4 + 2] * inv), f2bf(acc[c4 * 4 + 3] * inv) };
    *(short4v*)&dst[c4 * 4] = ov;
  }
}

// ---------------- LayerNorm + residual ----------------
// ln_res1: 2 bf16 partials (WO-proj split-K x2). ln_res2: 4 bf16 partials
// (MLP-down split-K x4). E residual read as bf16 (Ebf); x1 bf16-only (x1b).
__global__ __launch_bounds__(256) void ln_res1(
    const short* __restrict__ P0, const short* __restrict__ P1,
    const short* __restrict__ Eb,
    const float* __restrict__ gamma, const float* __restrict__ beta,
    short* __restrict__ x1b)
{
  int row = blockIdx.x, tid = threadIdx.x;
  int lane = tid & 63, wid = tid >> 6;
  size_t idx = (size_t)row * 1024 + tid * 4;
  short4v p0 = *(const short4v*)&P0[idx];
  short4v p1 = *(const short4v*)&P1[idx];
  float a[4];
  #pragma unroll
  for (int j = 0; j < 4; ++j)
    a[j] = bf2f(p0[j]) + bf2f(p1[j]);
  float s = a[0] + a[1] + a[2] + a[3];
  float q = a[0]*a[0] + a[1]*a[1] + a[2]*a[2] + a[3]*a[3];
  #pragma unroll
  for (int off = 1; off < 64; off <<= 1) { s += __shfl_xor(s, off, 64); q += __shfl_xor(q, off, 64); }
  __shared__ float red[8];
  if (lane == 0) { red[wid] = s; red[4 + wid] = q; }
  __syncthreads();
  s = red[0] + red[1] + red[2] + red[3];
  q = red[4] + red[5] + red[6] + red[7];
  float mean = s * (1.f / 1024.f);
  float var = q * (1.f / 1024.f) - mean * mean;
  float rstd = rsqrtf(var + 1e-5f);
  short4v ev = *(const short4v*)&Eb[idx];
  float4 gv = *(const float4*)&gamma[tid * 4];
  float4 bv = *(const float4*)&beta[tid * 4];
  float o0 = bf2f(ev[0]) + gv.x * (a[0] - mean) * rstd + bv.x;
  float o1 = bf2f(ev[1]) + gv.y * (a[1] - mean) * rstd + bv.y;
  float o2 = bf2f(ev[2]) + gv.z * (a[2] - mean) * rstd + bv.z;
  float o3 = bf2f(ev[3]) + gv.w * (a[3] - mean) * rstd + bv.w;
  short4v xb = { f2bf(o0), f2bf(o1), f2bf(o2), f2bf(o3) };
  *(short4v*)&x1b[idx] = xb;
}

__global__ __launch_bounds__(256) void ln_res2(
    const short* __restrict__ M0, const short* __restrict__ M1,
    const short* __restrict__ M2, const short* __restrict__ M3,
    const float* __restrict__ bias, const short* __restrict__ x1b,
    const float* __restrict__ gamma, const float* __restrict__ beta,
    float* __restrict__ out)
{
  int row = blockIdx.x, tid = threadIdx.x;
  int lane = tid & 63, wid = tid >> 6;
  size_t idx = (size_t)row * 1024 + tid * 4;
  short4v m0 = *(const short4v*)&M0[idx];
  short4v m1 = *(const short4v*)&M1[idx];
  short4v m2 = *(const short4v*)&M2[idx];
  short4v m3 = *(const short4v*)&M3[idx];
  float4 bb = *(const float4*)&bias[tid * 4];
  float a[4];
  a[0] = bf2f(m0[0]) + bf2f(m1[0]) + bf2f(m2[0]) + bf2f(m3[0]) + bb.x;
  a[1] = bf2f(m0[1]) + bf2f(m1[1]) + bf2f(m2[1]) + bf2f(m3[1]) + bb.y;
  a[2] = bf2f(m0[2]) + bf2f(m1[2]) + bf2f(m2[2]) + bf2f(m3[2]) + bb.z;
  a[3] = bf2f(m0[3]) + bf2f(m1[3]) + bf2f(m2[3]) + bf2f(m3[3]) + bb.w;
  float s = a[0] + a[1] + a[2] + a[3];
  float q = a[0]*a[0] + a[1]*a[1] + a[2]*a[2] + a[3]*a[3];
  #pragma unroll
  for (int off = 1; off < 64; off <<= 1) { s += __shfl_xor(s, off, 64); q += __shfl_xor(q, off, 64); }
  __shared__ float red[8];
  if (lane == 0) { red[wid] = s; red[4 + wid] = q; }
  __syncthreads();
  s = red[0] + red[1] + red[2] + red[3];
  q = red[4] + red[5] + red[6] + red[7];
  float mean = s * (1.f / 1024.f);
  float var = q * (1.f / 1024.f) - mean * mean;
  float rstd = rsqrtf(var + 1e-5f);
  short4v xv = *(const short4v*)&x1b[idx];
  float4 gv = *(const float4*)&gamma[tid * 4];
  float4 bv = *(const float4*)&beta[tid * 4];
  float4 ov = { bf2f(xv[0]) + gv.x * (a[0] - mean) * rstd + bv.x,
                bf2f(xv[1]) + gv.y * (a[1] - mean) * rstd + bv.y,
                bf2f(xv[2]) + gv.z * (a[2] - mean) * rstd + bv.z,
                bf2f(xv[3]) + gv.w * (a[3] - mean) * rstd + bv.w };
  *(float4*)&out[idx] = ov;
}

// ---------------- launch ----------------
extern "C" void kernel_launch(void* const* d_in, const int* in_sizes, int n_in,
                              void* d_out, int out_size, void* d_ws, size_t ws_size,
                              hipStream_t stream)
{
  (void)in_sizes; (void)n_in; (void)out_size;
  const int S = 2048, D = 1024, DM = 4096, H = 16;
  const size_t MB = 1u << 20;
  const float* E   = (const float*)d_in[0];
  const float* W_Q = (const float*)d_in[2];
  const float* W_K = (const float*)d_in[3];
  const float* W_V = (const float*)d_in[4];
  const float* W_O = (const float*)d_in[5];
  const float* H_Q = (const float*)d_in[6];
  const float* H_K = (const float*)d_in[7];
  const float* H_V = (const float*)d_in[8];
  const float* L1w = (const float*)d_in[9];
  const float* L1b = (const float*)d_in[10];
  const float* L2w = (const float*)d_in[11];
  const float* L2b = (const float*)d_in[12];
  const float* g1  = (const float*)d_in[13];
  const float* b1  = (const float*)d_in[14];
  const float* g2  = (const float*)d_in[15];
  const float* b2  = (const float*)d_in[16];

  char* base = (char*)d_ws;
  if (ws_size < 90 * MB) return;  // loud failure if workspace too small

  short* Ebf  = (short*)(base + 0 * MB);
  short* TWq  = (short*)(base + 4 * MB);   // W_Q^T bf16 [k][d]
  short* TWk  = (short*)(base + 6 * MB);
  short* TWv  = (short*)(base + 8 * MB);
  short* Wob  = (short*)(base + 10 * MB);
  short* Hqb  = (short*)(base + 12 * MB);
  short* Hkb  = (short*)(base + 14 * MB);
  short* Hvb  = (short*)(base + 16 * MB);
  short* L1wb = (short*)(base + 18 * MB);
  short* L2wb = (short*)(base + 26 * MB);
  short* Cq   = (short*)(base + 34 * MB);  // combined weight H_q @ W_Q, [e][k]
  short* Ck   = (short*)(base + 36 * MB);
  short* Cv   = (short*)(base + 38 * MB);
  short* qh   = (short*)(base + 46 * MB);
  short* kh   = (short*)(base + 50 * MB);
  short* vtb  = (short*)(base + 54 * MB);  // V^T per head: [H*64][S]
  short* obuf = (short*)(base + 58 * MB);
  short* x1b  = (short*)(base + 62 * MB);
  short* hbuf = (short*)(base + 74 * MB);  // [74,90)
  // WO-proj bf16 partials (split-K x2): alias hbuf region (dead then).
  short* WOP0 = (short*)(base + 74 * MB);
  short* WOP1 = (short*)(base + 82 * MB);
  // MLP-down bf16 partials (split-K x4): alias Cq..x1b region (dead then).
  short* MP0  = (short*)(base + 34 * MB);
  short* MP1  = (short*)(base + 42 * MB);
  short* MP2  = (short*)(base + 50 * MB);
  short* MP3  = (short*)(base + 58 * MB);
  // attention partials: live ONLY between flash_attn and attn_combine.
  short* Opart = (short*)(base + 66 * MB);  // 960 slots x 64x64 bf16 = 7.5 MB
  float* Ml    = (float*)(base + 86 * MB);  // 960 x 128 f32 = 0.48 MB

  PrepArgs pa;
  pa.j[0] = { E,   Ebf,  S * D / 4 };
  pa.j[1] = { W_O, Wob,  D * D / 4 };
  pa.j[2] = { H_Q, Hqb,  D * D / 4 };
  pa.j[3] = { H_K, Hkb,  D * D / 4 };
  pa.j[4] = { H_V, Hvb,  D * D / 4 };
  pa.j[5] = { L1w, L1wb, DM * D / 4 };
  pa.j[6] = { L2w, L2wb, DM * D / 4 };
  pa.n = 7;
  pa.tsrc[0] = W_Q; pa.tsrc[1] = W_K; pa.tsrc[2] = W_V;
  pa.tdst[0] = TWq; pa.tdst[1] = TWk; pa.tdst[2] = TWv;
  prep_kernel<<<2048 + 768, 256, 0, stream>>>(pa);

  GemmArgs ga;

  // weight combine: C_x = H_x @ W_X (so x_head = E @ C_x^T), BM=64 tiles:
  // grid 8 x 16 x 3 = 384 blocks (1.5/CU) with NO split-K / NO fold.
  ga = {};
  ga.A[0] = Hqb; ga.A[1] = Hkb; ga.A[2] = Hvb;
  ga.B[0] = TWq; ga.B[1] = TWk; ga.B[2] = TWv;
  ga.C[0] = Cq;  ga.C[1] = Ck;  ga.C[2] = Cv;
  ga.M = D; ga.N = D; ga.K = D; ga.klen = D;
  for (int z = 0; z < 6; ++z) ga.kb[z] = 0;
  gemm_bt<0, true, true, 64><<<dim3(D / 128, D / 64, 3), 256, 0, stream>>>(ga);

  // fused projections: qh/kh (normal store) + vtb (transposed store), one
  // launch, BM=64: grid 8 x 32 x 3 = 768 blocks = 3 x 256 -> LDS 48 KB gives
  // 3 blocks/CU = EXACTLY one full round, counted-vmcnt pipeline retained.
  ga = {};
  ga.A[0] = Ebf; ga.A[1] = Ebf; ga.A[2] = Ebf;
  ga.B[0] = Cq;  ga.B[1] = Ck;  ga.B[2] = Cv;
  ga.C[0] = qh;  ga.C[1] = kh;  ga.C[2] = vtb;
  ga.M = S; ga.N = D; ga.K = D; ga.klen = D;
  for (int z = 0; z < 6; ++z) ga.kb[z] = 0;
  gemm_bt<4, true, true, 64><<<dim3(D / 128, S / 64, 3), 256, 0, stream>>>(ga);

  // causal attention, chunks of <=12 K/V-tiles (60 chunks/head, 960 blocks)
  flash_attn<<<dim3(H, 60), 256, 0, stream>>>(qh, kh, vtb, obuf, Opart, Ml);
  // combine chunks for q-tiles 12..31
  attn_combine<<<dim3(H, 20), 256, 0, stream>>>(Opart, Ml, obuf);

  // output projection, BM=64 + split-K x2 -> bf16 partials
  // (grid 8 x 32 x 2 = 512 blocks, klen 512 = 8 K-steps; shallow-K so
  // BM=64 staging penalty is small vs partial-traffic halving)
  ga = {};
  ga.A[0] = obuf; ga.A[1] = obuf;
  ga.B[0] = Wob;  ga.B[1] = Wob;
  ga.C[0] = WOP0; ga.C[1] = WOP1;
  ga.M = S; ga.N = D; ga.K = D; ga.klen = D / 2;
  for (int z = 0; z < 6; ++z) ga.kb[z] = (z & 1) * (D / 2);
  gemm_bt<2, true, true, 64><<<dim3(D / 128, S / 64, 2), 256, 0, stream>>>(ga);

  // LN1 + residual (bf16 E, 2 partials) -> bf16 x1
  ln_res1<<<S, 256, 0, stream>>>(WOP0, WOP1, Ebf, g1, b1, x1b);

  // MLP up + bias + relu (512 blocks, 2/CU) -> dbuf BM=128; swizzle OFF (N=4096)
  ga = {};
  ga.A[0] = x1b; ga.B[0] = L1wb; ga.C[0] = hbuf;
  ga.bias = L1b;
  ga.M = S; ga.N = DM; ga.K = D; ga.klen = D;
  for (int z = 0; z < 6; ++z) ga.kb[z] = 0;
  gemm_bt<1, false, true><<<dim3(DM / 128, S / 128, 1), 256, 0, stream>>>(ga);

  // MLP down: BM=128 + split-K x4 (round-18 lesson: deep-K needs the full
  // 128-row A-tile; BM=64 split-K x2 regressed 5 us on staging traffic)
  ga = {};
  ga.A[0] = hbuf; ga.A[1] = hbuf; ga.A[2] = hbuf; ga.A[3] = hbuf;
  ga.B[0] = L2wb; ga.B[1] = L2wb; ga.B[2] = L2wb; ga.B[3] = L2wb;
  ga.C[0] = MP0;  ga.C[1] = MP1;  ga.C[2] = MP2;  ga.C[3] = MP3;
  ga.M = S; ga.N = D; ga.K = DM; ga.klen = DM / 4;
  for (int z = 0; z < 6; ++z) ga.kb[z] = z * (DM / 4);
  gemm_bt<2, true, true><<<dim3(D / 128, S / 128, 4), 256, 0, stream>>>(ga);

  // LN2 + bias + residual (bf16 x1) -> out (f32)
  ln_res2<<<S, 256, 0, stream>>>(MP0, MP1, MP2, MP3, L2b, x1b, g2, b2, (float*)d_out);
}